// Round 6
// baseline (2305.275 us; speedup 1.0000x reference)
//
#include <hip/hip_runtime.h>

#define NB   8
#define NP   8192
#define NS   2048
#define NK   16
#define DIN  64
#define DOUT 128
#define BN_EPS 1e-5f

#define MT   512            // mega-kernel block size
#define FP   (NP / MT)      // 16 fps points per thread
#define FW   (MT / 64)      // 8 waves
#define KJ   (NP / MT)      // 16 knn points per thread
#define KBINS 64
#define MAXC 512

// ---------------- K0: fold BN into weights, transpose to [k][o] ----------------
__global__ void fold_weights_kernel(const float* __restrict__ W, const float* __restrict__ bias,
                                    const float* __restrict__ gamma, const float* __restrict__ beta,
                                    const float* __restrict__ rmean, const float* __restrict__ rvar,
                                    float* __restrict__ Wt, float* __restrict__ Cb)
{
    int i = blockIdx.x * 256 + threadIdx.x;
    if (i < DIN * DOUT) {
        int o = i & (DOUT - 1);
        int k = i >> 7;
        float sc = gamma[o] * rsqrtf(rvar[o] + BN_EPS);
        Wt[i] = W[o * DIN + k] * sc;            // Wt[k*128 + o]
        if (i < DOUT) {
            Cb[i] = (bias[i] - rmean[i]) * sc + beta[i];
        }
    }
}

// ---------------- f64-packed argmax helpers --------------------------------------
// packed u64 = (fp32 dist bits << 32) | ~idx, as double (sign bit 0 -> numeric
// order == u64 order): fmax == (max dist, tie -> min idx).
__device__ __forceinline__ double pack_di(float d, unsigned lo)
{
    unsigned long long u = ((unsigned long long)__float_as_uint(d) << 32) | lo;
    return __longlong_as_double((long long)u);
}

template<int CTRL, int RMASK>
__device__ __forceinline__ double dpp_max_f64(double v)
{
    unsigned long long u = (unsigned long long)__double_as_longlong(v);
    unsigned hi = (unsigned)(u >> 32), lo = (unsigned)u;
    unsigned th = (unsigned)__builtin_amdgcn_update_dpp((int)hi, (int)hi, CTRL, RMASK, 0xF, false);
    unsigned tl = (unsigned)__builtin_amdgcn_update_dpp((int)lo, (int)lo, CTRL, RMASK, 0xF, false);
    double o = __longlong_as_double((long long)(((unsigned long long)th << 32) | tl));
    return fmax(v, o);
}

__device__ __forceinline__ int knn_bin(float d)
{
    int e = (int)(__float_as_uint(d) >> 23) - 90;   // monotone, clamped octave bins
    return e < 0 ? 0 : (e > 63 ? 63 : e);
}

// ---------------- mega kernel: fps (blocks 0-7) + mlp + knn consumers ----------
struct FpsS {
    float4 sxyz[NP];                    // 128 KB
    int sel[NS];                        // 8 KB
    unsigned long long rv64[2][FW];
};
struct KnnS {
    float sdist[NP];                    // 32 KB
    unsigned hist[32][KBINS];           // 8 KB
    float cd[MAXC];
    int   ci[MAXC];
    unsigned ccnt;
    int cut;
};
struct MlpS { float sf[4][DIN]; };
union MegaS { FpsS f; KnnS k; MlpS m; };

__global__ __launch_bounds__(MT, 1)
void mega_kernel(const float* __restrict__ coords, float* __restrict__ out_coords,
                 const float* __restrict__ feat, const float* __restrict__ Wt,
                 const float* __restrict__ Cb, float* __restrict__ h,
                 int* __restrict__ knn, unsigned* __restrict__ flags, int nmlp)
{
#pragma clang fp contract(off)
    __shared__ MegaS smem;
    const int t = threadIdx.x;

    if (blockIdx.x < NB) {
        // ================= FPS producer (1 block per batch) =================
        const int b = blockIdx.x;
        const float* cb = coords + (size_t)b * NP * 3;

        for (int i = t; i < NP; i += MT)
            smem.f.sxyz[i] = make_float4(cb[i * 3 + 0], cb[i * 3 + 1], cb[i * 3 + 2], 0.0f);
        __syncthreads();

        float px[FP], py[FP], pz[FP], dist[FP];
#pragma unroll
        for (int k = 0; k < FP; ++k) {
            float4 p = smem.f.sxyz[t + k * MT];
            px[k] = p.x; py[k] = p.y; pz[k] = p.z;
            dist[k] = 1e10f;
        }

        const int wave = t >> 6, lane = t & 63;
        int cur = 0;

        for (int s = 0; s < NS; ++s) {
            if (t == 0) smem.f.sel[s] = cur;
            const float4 cc = smem.f.sxyz[cur];
            const float cx = cc.x, cy = cc.y, cz = cc.z;

            // min-dist update + thread argmax (strict >, ascending k -> min idx)
            float m = -1.0f; int kk = 0;
#pragma unroll
            for (int k = 0; k < FP; ++k) {
                float dx = px[k] - cx, dy = py[k] - cy, dz = pz[k] - cz;
                float d = fmaf(dz, dz, fmaf(dy, dy, dx * dx));
                float nd = dist[k] < d ? dist[k] : d;
                dist[k] = nd;
                if (nd > m) { m = nd; kk = k; }
            }
            double best = pack_di(m, ~(unsigned)(t + kk * MT));

            // wave argmax: 6 DPP f64-max levels -> lane 63 holds wave max
            best = dpp_max_f64<0xB1,  0xF>(best);  // quad_perm xor1
            best = dpp_max_f64<0x4E,  0xF>(best);  // quad_perm xor2
            best = dpp_max_f64<0x124, 0xF>(best);  // row_ror:4
            best = dpp_max_f64<0x128, 0xF>(best);  // row_ror:8
            best = dpp_max_f64<0x142, 0xA>(best);  // row_bcast15
            best = dpp_max_f64<0x143, 0xC>(best);  // row_bcast31

            int pb = s & 1;
            if (lane == 63) smem.f.rv64[pb][wave] = (unsigned long long)__double_as_longlong(best);
            __syncthreads();

            // cross-wave: b64 read of partial[lane&7], 4 DPP levels over row-of-16
            double g = __longlong_as_double((long long)smem.f.rv64[pb][lane & 7]);
            g = dpp_max_f64<0xB1,  0xF>(g);
            g = dpp_max_f64<0x4E,  0xF>(g);
            g = dpp_max_f64<0x124, 0xF>(g);
            g = dpp_max_f64<0x128, 0xF>(g);
            cur = (int)~(unsigned)(unsigned long long)__double_as_longlong(g);

            // publish a 32-query granule (wave 0 only: release orders the wave's
            // own coord stores before the flag bump — no cross-wave fence needed)
            if ((s & 31) == 31) {
                int base = s - 31;
                if (t < 32) {
                    float4 p = smem.f.sxyz[smem.f.sel[base + t]];
                    float* dst = out_coords + ((size_t)b * NS + base + t) * 3;
                    dst[0] = p.x; dst[1] = p.y; dst[2] = p.z;
                }
                if (t == 0)
                    __hip_atomic_store(&flags[b], (unsigned)((s + 1) >> 5),
                                       __ATOMIC_RELEASE, __HIP_MEMORY_SCOPE_AGENT);
            }
        }
    } else if (blockIdx.x < NB + nmlp) {
        // ================= MLP (independent of fps) =================
        const int mb = blockIdx.x - NB;
        const int o = t & (DOUT - 1);
        const int r = t >> 7;                       // 0..3
        const size_t row0 = (size_t)mb * 4;

        if (t < 4 * DIN) smem.m.sf[t >> 6][t & 63] = feat[row0 * DIN + t];
        __syncthreads();

        float acc = Cb[o];
        const float4* f4 = (const float4*)smem.m.sf[r];
#pragma unroll
        for (int k4 = 0; k4 < DIN / 4; ++k4) {
            float4 f = f4[k4];
            acc = fmaf(f.x, Wt[(k4 * 4 + 0) * DOUT + o], acc);
            acc = fmaf(f.y, Wt[(k4 * 4 + 1) * DOUT + o], acc);
            acc = fmaf(f.z, Wt[(k4 * 4 + 2) * DOUT + o], acc);
            acc = fmaf(f.w, Wt[(k4 * 4 + 3) * DOUT + o], acc);
        }
        h[(row0 + r) * DOUT + o] = fmaxf(acc, 0.0f);
    } else {
        // ================= KNN consumer (spins until its query exists) =========
        const int qq = blockIdx.x - NB - nmlp;      // 0..NB*NS-1
        const int b = qq >> 11, s = qq & (NS - 1);
        const int q = b * NS + s;

        if (t == 0) {
            unsigned need = (unsigned)(s >> 5) + 1;
            while (__hip_atomic_load(&flags[b], __ATOMIC_ACQUIRE,
                                     __HIP_MEMORY_SCOPE_AGENT) < need)
                __builtin_amdgcn_s_sleep(8);
        }
        __syncthreads();

        const float* cb = coords + (size_t)b * NP * 3;
        const float* qp = out_coords + (size_t)q * 3;
        const float qx = qp[0], qy = qp[1], qz = qp[2];
        const int c = t & 31;

        for (int i = t; i < 32 * KBINS; i += MT) ((unsigned*)smem.k.hist)[i] = 0;
        if (t == 0) smem.k.ccnt = 0;
        __syncthreads();

        for (int j = 0; j < KJ; ++j) {
            int i = t + j * MT;
            float dx = cb[i * 3 + 0] - qx, dy = cb[i * 3 + 1] - qy, dz = cb[i * 3 + 2] - qz;
            float d = fmaf(dz, dz, fmaf(dy, dy, dx * dx));
            smem.k.sdist[i] = d;
            atomicAdd(&smem.k.hist[c][knn_bin(d)], 1u);
        }
        __syncthreads();

        if (t < 64) {
            unsigned total = 0;
#pragma unroll
            for (int cc = 0; cc < 32; ++cc) total += smem.k.hist[cc][t];
            unsigned incl = total;
#pragma unroll
            for (int off = 1; off < 64; off <<= 1) {
                unsigned n = __shfl_up(incl, off);
                if (t >= off) incl += n;
            }
            unsigned excl = incl - total;
            if (excl < NK && incl >= NK) smem.k.cut = t;
        }
        __syncthreads();

        const int cut = smem.k.cut;
        for (int j = 0; j < KJ; ++j) {
            int i = t + j * MT;
            float d = smem.k.sdist[i];
            if (knn_bin(d) <= cut) {
                unsigned p = atomicAdd(&smem.k.ccnt, 1u);
                if (p < MAXC) { smem.k.cd[p] = d; smem.k.ci[p] = i; }
            }
        }
        __syncthreads();

        // parallel rank-select: rank = #{(dj,ij) < (d,i)}; unique ranks
        int cnt = (int)(smem.k.ccnt < (unsigned)MAXC ? smem.k.ccnt : (unsigned)MAXC);
        for (int p = t; p < cnt; p += MT) {
            float d = smem.k.cd[p]; int idx = smem.k.ci[p];
            int rank = 0;
            for (int j = 0; j < cnt; ++j) {
                float dj = smem.k.cd[j]; int ij = smem.k.ci[j];
                rank += (dj < d || (dj == d && ij < idx)) ? 1 : 0;
            }
            if (rank < NK) knn[(size_t)q * NK + rank] = idx;
        }
    }
}

// ---------------- gather precomputed h + max-pool ----------------
__global__ __launch_bounds__(128)
void gather_max_kernel(const float* __restrict__ h, const int* __restrict__ knn,
                       float* __restrict__ outF)
{
    const int q = blockIdx.x, o = threadIdx.x, b = q >> 11;
    __shared__ int sidx[NK];
    if (o < NK) sidx[o] = knn[(size_t)q * NK + o];
    __syncthreads();
    float m = -3.4e38f;
#pragma unroll
    for (int n = 0; n < NK; ++n) {
        float v = h[((size_t)b * NP + sidx[n]) * DOUT + o];
        m = fmaxf(m, v);
    }
    outF[(size_t)q * DOUT + o] = m;
}

// ---------------- fallback if ws too small — fused gather + MLP + max ----------
__global__ __launch_bounds__(128)
void fused_gather_mlp_kernel(const float* __restrict__ feat, const float* __restrict__ Wt,
                             const float* __restrict__ Cb, const int* __restrict__ knn,
                             float* __restrict__ outF)
{
    const int q = blockIdx.x, o = threadIdx.x, b = q >> 11;
    __shared__ int sidx[NK];
    __shared__ float sf[NK][DIN];
    if (o < NK) sidx[o] = knn[(size_t)q * NK + o];
    __syncthreads();
    for (int j = o; j < NK * DIN; j += 128) {
        int n = j >> 6;
        sf[n][j & 63] = feat[((size_t)b * NP + sidx[n]) * DIN + (j & 63)];
    }
    __syncthreads();
    const float cb0 = Cb[o];
    float m = -3.4e38f;
    for (int n = 0; n < NK; ++n) {
        float acc = cb0;
        const float4* f4 = (const float4*)sf[n];
#pragma unroll
        for (int k4 = 0; k4 < DIN / 4; ++k4) {
            float4 f = f4[k4];
            acc = fmaf(f.x, Wt[(k4 * 4 + 0) * DOUT + o], acc);
            acc = fmaf(f.y, Wt[(k4 * 4 + 1) * DOUT + o], acc);
            acc = fmaf(f.z, Wt[(k4 * 4 + 2) * DOUT + o], acc);
            acc = fmaf(f.w, Wt[(k4 * 4 + 3) * DOUT + o], acc);
        }
        m = fmaxf(m, fmaxf(acc, 0.0f));
    }
    outF[(size_t)q * DOUT + o] = m;
}

extern "C" void kernel_launch(void* const* d_in, const int* in_sizes, int n_in,
                              void* d_out, int out_size, void* d_ws, size_t ws_size,
                              hipStream_t stream)
{
    const float* coords = (const float*)d_in[0];
    const float* feat   = (const float*)d_in[1];
    const float* W      = (const float*)d_in[2];
    const float* bias   = (const float*)d_in[3];
    const float* gamma  = (const float*)d_in[4];
    const float* beta   = (const float*)d_in[5];
    const float* rmean  = (const float*)d_in[6];
    const float* rvar   = (const float*)d_in[7];

    float* out_coords = (float*)d_out;                    // [8,2048,3]
    float* out_feat   = out_coords + (size_t)NB * NS * 3; // [8,2048,128]

    char* ws = (char*)d_ws;
    float*    Wt    = (float*)ws;                         // 32 KB
    float*    Cb    = (float*)(ws + 32768);               // 512 B
    unsigned* flags = (unsigned*)(ws + 40960);            // 32 B
    int*      knnb  = (int*)(ws + 65536);                 // 1 MB
    size_t knn_bytes = (size_t)NB * NS * NK * 4;
    float*    h     = (float*)(ws + 65536 + knn_bytes);   // 33.5 MB
    size_t need_h = (size_t)NB * NP * DOUT * 4;
    bool pathA = ws_size >= 65536 + knn_bytes + need_h;
    int nmlp = pathA ? (NB * NP / 4) : 0;                 // 16384 mlp blocks

    hipMemsetAsync(flags, 0, NB * sizeof(unsigned), stream);
    fold_weights_kernel<<<(DIN * DOUT + 255) / 256, 256, 0, stream>>>(
        W, bias, gamma, beta, rmean, rvar, Wt, Cb);
    mega_kernel<<<NB + nmlp + NB * NS, MT, 0, stream>>>(
        coords, out_coords, feat, Wt, Cb, h, knnb, flags, nmlp);
    if (pathA)
        gather_max_kernel<<<NB * NS, 128, 0, stream>>>(h, knnb, out_feat);
    else
        fused_gather_mlp_kernel<<<NB * NS, 128, 0, stream>>>(feat, Wt, Cb, knnb, out_feat);
}

// Round 7
// 1791.142 us; speedup vs baseline: 1.2870x; 1.2870x over previous
//
#include <hip/hip_runtime.h>

#define NB   8
#define NP   8192
#define NS   2048
#define NK   16
#define DIN  64
#define DOUT 128
#define BN_EPS 1e-5f

#define MT   512            // mega-kernel block size
#define NW   248            // worker blocks (grid = 8 fps + 248 workers = 256 CUs)
#define FP   (NP / MT)      // 16 fps points per thread
#define FW   (MT / 64)      // 8 waves
#define KJ   (NP / MT)      // 16 knn points per thread
#define KBINS 64
#define MAXC 512

// ---------------- K0: fold BN into weights, transpose to [k][o] ----------------
__global__ void fold_weights_kernel(const float* __restrict__ W, const float* __restrict__ bias,
                                    const float* __restrict__ gamma, const float* __restrict__ beta,
                                    const float* __restrict__ rmean, const float* __restrict__ rvar,
                                    float* __restrict__ Wt, float* __restrict__ Cb)
{
    int i = blockIdx.x * 256 + threadIdx.x;
    if (i < DIN * DOUT) {
        int o = i & (DOUT - 1);
        int k = i >> 7;
        float sc = gamma[o] * rsqrtf(rvar[o] + BN_EPS);
        Wt[i] = W[o * DIN + k] * sc;            // Wt[k*128 + o]
        if (i < DOUT) {
            Cb[i] = (bias[i] - rmean[i]) * sc + beta[i];
        }
    }
}

// ---------------- f64-packed argmax helpers --------------------------------------
// packed u64 = (fp32 dist bits << 32) | ~idx, as double (sign bit 0 -> numeric
// order == u64 order): fmax == (max dist, tie -> min idx).
__device__ __forceinline__ double pack_di(float d, unsigned lo)
{
    unsigned long long u = ((unsigned long long)__float_as_uint(d) << 32) | lo;
    return __longlong_as_double((long long)u);
}

template<int CTRL, int RMASK>
__device__ __forceinline__ double dpp_max_f64(double v)
{
    unsigned long long u = (unsigned long long)__double_as_longlong(v);
    unsigned hi = (unsigned)(u >> 32), lo = (unsigned)u;
    unsigned th = (unsigned)__builtin_amdgcn_update_dpp((int)hi, (int)hi, CTRL, RMASK, 0xF, false);
    unsigned tl = (unsigned)__builtin_amdgcn_update_dpp((int)lo, (int)lo, CTRL, RMASK, 0xF, false);
    double o = __longlong_as_double((long long)(((unsigned long long)th << 32) | tl));
    return fmax(v, o);
}

__device__ __forceinline__ int knn_bin(float d)
{
    int e = (int)(__float_as_uint(d) >> 23) - 90;   // monotone, clamped octave bins
    return e < 0 ? 0 : (e > 63 ? 63 : e);
}

// ---------------- mega kernel: 8 fps producers + 248 persistent workers --------
struct FpsS {
    float4 sxyz[NP];                    // 128 KB
    int sel[NS];                        // 8 KB
    unsigned long long rv64[2][FW];
};
struct KnnS {
    float sdist[NP];                    // 32 KB
    unsigned hist[32][KBINS];           // 8 KB
    float cd[MAXC];
    int   ci[MAXC];
    unsigned ccnt;
    int cut;
};
struct MlpS { float sf[4][DIN]; };
union MegaS { FpsS f; KnnS k; MlpS m; };
// union = ~139 KB -> exactly 1 block/CU; grid 256 -> all blocks co-resident,
// so producer progress never depends on dispatch order (deadlock-safe).

__global__ __launch_bounds__(MT, 1)
void mega_kernel(const float* __restrict__ coords, float* __restrict__ out_coords,
                 const float* __restrict__ feat, const float* __restrict__ Wt,
                 const float* __restrict__ Cb, float* __restrict__ h,
                 int* __restrict__ knn, unsigned* __restrict__ flags, int do_mlp)
{
#pragma clang fp contract(off)
    __shared__ MegaS smem;
    const int t = threadIdx.x;

    if (blockIdx.x < NB) {
        // ================= FPS producer (1 block per batch) =================
        const int b = blockIdx.x;
        const float* cb = coords + (size_t)b * NP * 3;

        for (int i = t; i < NP; i += MT)
            smem.f.sxyz[i] = make_float4(cb[i * 3 + 0], cb[i * 3 + 1], cb[i * 3 + 2], 0.0f);
        __syncthreads();

        float px[FP], py[FP], pz[FP], dist[FP];
#pragma unroll
        for (int k = 0; k < FP; ++k) {
            float4 p = smem.f.sxyz[t + k * MT];
            px[k] = p.x; py[k] = p.y; pz[k] = p.z;
            dist[k] = 1e10f;
        }

        const int wave = t >> 6, lane = t & 63;
        const unsigned nt = ~(unsigned)t;          // ~(t + k*MT) == nt - k*MT
        int cur = 0;

        for (int s = 0; s < NS; ++s) {
            if (t == 0) smem.f.sel[s] = cur;
            const float4 cc = smem.f.sxyz[cur];
            const float cx = cc.x, cy = cc.y, cz = cc.z;

            // min-dist update + packed argmax (dual f64 fmax chains — R5 form)
            double best0 = 0.0, best1 = 0.0;
#pragma unroll
            for (int k = 0; k < FP; ++k) {
                float dx = px[k] - cx, dy = py[k] - cy, dz = pz[k] - cz;
                float d = fmaf(dz, dz, fmaf(dy, dy, dx * dx));
                float nd = dist[k] < d ? dist[k] : d;
                dist[k] = nd;
                double pd = pack_di(nd, nt - (unsigned)(k * MT));
                if (k & 1) best1 = fmax(best1, pd);
                else       best0 = fmax(best0, pd);
            }
            double best = fmax(best0, best1);

            // wave argmax: 6 DPP f64-max levels -> lane 63 holds wave max
            best = dpp_max_f64<0xB1,  0xF>(best);  // quad_perm xor1
            best = dpp_max_f64<0x4E,  0xF>(best);  // quad_perm xor2
            best = dpp_max_f64<0x124, 0xF>(best);  // row_ror:4
            best = dpp_max_f64<0x128, 0xF>(best);  // row_ror:8
            best = dpp_max_f64<0x142, 0xA>(best);  // row_bcast15
            best = dpp_max_f64<0x143, 0xC>(best);  // row_bcast31

            int pb = s & 1;
            if (lane == 63) smem.f.rv64[pb][wave] = (unsigned long long)__double_as_longlong(best);
            __syncthreads();

            // cross-wave: b64 read of partial[lane&7], 4 DPP levels over row-of-16
            double g = __longlong_as_double((long long)smem.f.rv64[pb][lane & 7]);
            g = dpp_max_f64<0xB1,  0xF>(g);
            g = dpp_max_f64<0x4E,  0xF>(g);
            g = dpp_max_f64<0x124, 0xF>(g);
            g = dpp_max_f64<0x128, 0xF>(g);
            cur = (int)~(unsigned)(unsigned long long)__double_as_longlong(g);

            // publish a 32-query granule (wave 0 only: program-order release
            // covers the wave's own coord stores)
            if ((s & 31) == 31) {
                int base = s - 31;
                if (t < 32) {
                    float4 p = smem.f.sxyz[smem.f.sel[base + t]];
                    float* dst = out_coords + ((size_t)b * NS + base + t) * 3;
                    dst[0] = p.x; dst[1] = p.y; dst[2] = p.z;
                }
                if (t == 0)
                    __hip_atomic_store(&flags[b * 16], (unsigned)((s + 1) >> 5),
                                       __ATOMIC_RELEASE, __HIP_MEMORY_SCOPE_AGENT);
            }
        }
    } else {
        // ================= persistent worker =================
        const int wid = blockIdx.x - NB;           // 0..247

        // ---- phase 1: MLP (independent of fps) ----
        if (do_mlp) {
            const int o = t & (DOUT - 1);
            const int r = t >> 7;                  // 0..3
            for (int gg = wid; gg < NB * NP / 4; gg += NW) {
                const size_t row0 = (size_t)gg * 4;
                if (t < 4 * DIN) smem.m.sf[t >> 6][t & 63] = feat[row0 * DIN + t];
                __syncthreads();
                float acc = Cb[o];
                const float4* f4 = (const float4*)smem.m.sf[r];
#pragma unroll
                for (int k4 = 0; k4 < DIN / 4; ++k4) {
                    float4 f = f4[k4];
                    acc = fmaf(f.x, Wt[(k4 * 4 + 0) * DOUT + o], acc);
                    acc = fmaf(f.y, Wt[(k4 * 4 + 1) * DOUT + o], acc);
                    acc = fmaf(f.z, Wt[(k4 * 4 + 2) * DOUT + o], acc);
                    acc = fmaf(f.w, Wt[(k4 * 4 + 3) * DOUT + o], acc);
                }
                h[(row0 + r) * DOUT + o] = fmaxf(acc, 0.0f);
                __syncthreads();
            }
        }

        // ---- phase 2: KNN over assigned queries, ascending s (tracks producer) ----
        const int c = t & 31;
        for (int s = wid; s < NS; s += NW) {
            const unsigned need = (unsigned)(s >> 5) + 1;
            for (int b = 0; b < NB; ++b) {
                if (t == 0) {
                    while (__hip_atomic_load(&flags[b * 16], __ATOMIC_ACQUIRE,
                                             __HIP_MEMORY_SCOPE_AGENT) < need)
                        __builtin_amdgcn_s_sleep(32);
                }
                __syncthreads();

                const int q = b * NS + s;
                const float* cb = coords + (size_t)b * NP * 3;
                const float* qp = out_coords + (size_t)q * 3;
                const float qx = qp[0], qy = qp[1], qz = qp[2];

                for (int i = t; i < 32 * KBINS; i += MT) ((unsigned*)smem.k.hist)[i] = 0;
                if (t == 0) smem.k.ccnt = 0;
                __syncthreads();

                for (int j = 0; j < KJ; ++j) {
                    int i = t + j * MT;
                    float dx = cb[i * 3 + 0] - qx, dy = cb[i * 3 + 1] - qy, dz = cb[i * 3 + 2] - qz;
                    float d = fmaf(dz, dz, fmaf(dy, dy, dx * dx));
                    smem.k.sdist[i] = d;
                    atomicAdd(&smem.k.hist[c][knn_bin(d)], 1u);
                }
                __syncthreads();

                if (t < 64) {
                    unsigned total = 0;
#pragma unroll
                    for (int cc = 0; cc < 32; ++cc) total += smem.k.hist[cc][t];
                    unsigned incl = total;
#pragma unroll
                    for (int off = 1; off < 64; off <<= 1) {
                        unsigned n = __shfl_up(incl, off);
                        if (t >= off) incl += n;
                    }
                    unsigned excl = incl - total;
                    if (excl < NK && incl >= NK) smem.k.cut = t;
                }
                __syncthreads();

                const int cut = smem.k.cut;
                for (int j = 0; j < KJ; ++j) {
                    int i = t + j * MT;
                    float d = smem.k.sdist[i];
                    if (knn_bin(d) <= cut) {
                        unsigned p = atomicAdd(&smem.k.ccnt, 1u);
                        if (p < MAXC) { smem.k.cd[p] = d; smem.k.ci[p] = i; }
                    }
                }
                __syncthreads();

                // parallel rank-select: rank = #{(dj,ij) < (d,i)}; unique ranks
                int cnt = (int)(smem.k.ccnt < (unsigned)MAXC ? smem.k.ccnt : (unsigned)MAXC);
                for (int p = t; p < cnt; p += MT) {
                    float d = smem.k.cd[p]; int idx = smem.k.ci[p];
                    int rank = 0;
                    for (int j = 0; j < cnt; ++j) {
                        float dj = smem.k.cd[j]; int ij = smem.k.ci[j];
                        rank += (dj < d || (dj == d && ij < idx)) ? 1 : 0;
                    }
                    if (rank < NK) knn[(size_t)q * NK + rank] = idx;
                }
                __syncthreads();
            }
        }
    }
}

// ---------------- gather precomputed h + max-pool ----------------
__global__ __launch_bounds__(128)
void gather_max_kernel(const float* __restrict__ h, const int* __restrict__ knn,
                       float* __restrict__ outF)
{
    const int q = blockIdx.x, o = threadIdx.x, b = q >> 11;
    __shared__ int sidx[NK];
    if (o < NK) sidx[o] = knn[(size_t)q * NK + o];
    __syncthreads();
    float m = -3.4e38f;
#pragma unroll
    for (int n = 0; n < NK; ++n) {
        float v = h[((size_t)b * NP + sidx[n]) * DOUT + o];
        m = fmaxf(m, v);
    }
    outF[(size_t)q * DOUT + o] = m;
}

// ---------------- fallback if ws too small — fused gather + MLP + max ----------
__global__ __launch_bounds__(128)
void fused_gather_mlp_kernel(const float* __restrict__ feat, const float* __restrict__ Wt,
                             const float* __restrict__ Cb, const int* __restrict__ knn,
                             float* __restrict__ outF)
{
    const int q = blockIdx.x, o = threadIdx.x, b = q >> 11;
    __shared__ int sidx[NK];
    __shared__ float sf[NK][DIN];
    if (o < NK) sidx[o] = knn[(size_t)q * NK + o];
    __syncthreads();
    for (int j = o; j < NK * DIN; j += 128) {
        int n = j >> 6;
        sf[n][j & 63] = feat[((size_t)b * NP + sidx[n]) * DIN + (j & 63)];
    }
    __syncthreads();
    const float cb0 = Cb[o];
    float m = -3.4e38f;
    for (int n = 0; n < NK; ++n) {
        float acc = cb0;
        const float4* f4 = (const float4*)sf[n];
#pragma unroll
        for (int k4 = 0; k4 < DIN / 4; ++k4) {
            float4 f = f4[k4];
            acc = fmaf(f.x, Wt[(k4 * 4 + 0) * DOUT + o], acc);
            acc = fmaf(f.y, Wt[(k4 * 4 + 1) * DOUT + o], acc);
            acc = fmaf(f.z, Wt[(k4 * 4 + 2) * DOUT + o], acc);
            acc = fmaf(f.w, Wt[(k4 * 4 + 3) * DOUT + o], acc);
        }
        m = fmaxf(m, fmaxf(acc, 0.0f));
    }
    outF[(size_t)q * DOUT + o] = m;
}

extern "C" void kernel_launch(void* const* d_in, const int* in_sizes, int n_in,
                              void* d_out, int out_size, void* d_ws, size_t ws_size,
                              hipStream_t stream)
{
    const float* coords = (const float*)d_in[0];
    const float* feat   = (const float*)d_in[1];
    const float* W      = (const float*)d_in[2];
    const float* bias   = (const float*)d_in[3];
    const float* gamma  = (const float*)d_in[4];
    const float* beta   = (const float*)d_in[5];
    const float* rmean  = (const float*)d_in[6];
    const float* rvar   = (const float*)d_in[7];

    float* out_coords = (float*)d_out;                    // [8,2048,3]
    float* out_feat   = out_coords + (size_t)NB * NS * 3; // [8,2048,128]

    char* ws = (char*)d_ws;
    float*    Wt    = (float*)ws;                         // 32 KB
    float*    Cb    = (float*)(ws + 32768);               // 512 B
    unsigned* flags = (unsigned*)(ws + 40960);            // 8 flags, 64B apart
    int*      knnb  = (int*)(ws + 65536);                 // 1 MB
    size_t knn_bytes = (size_t)NB * NS * NK * 4;
    float*    h     = (float*)(ws + 65536 + knn_bytes);   // 33.5 MB
    size_t need_h = (size_t)NB * NP * DOUT * 4;
    bool pathA = ws_size >= 65536 + knn_bytes + need_h;

    hipMemsetAsync(flags, 0, 8 * 16 * sizeof(unsigned), stream);
    fold_weights_kernel<<<(DIN * DOUT + 255) / 256, 256, 0, stream>>>(
        W, bias, gamma, beta, rmean, rvar, Wt, Cb);
    mega_kernel<<<NB + NW, MT, 0, stream>>>(
        coords, out_coords, feat, Wt, Cb, h, knnb, flags, pathA ? 1 : 0);
    if (pathA)
        gather_max_kernel<<<NB * NS, 128, 0, stream>>>(h, knnb, out_feat);
    else
        fused_gather_mlp_kernel<<<NB * NS, 128, 0, stream>>>(feat, Wt, Cb, knnb, out_feat);
}

// Round 8
// 1644.643 us; speedup vs baseline: 1.4017x; 1.0891x over previous
//
#include <hip/hip_runtime.h>

#define NB   8
#define NP   8192
#define NS   2048
#define NK   16
#define DIN  64
#define DOUT 128
#define BN_EPS 1e-5f

#define MT   512            // mega-kernel block size
#define NW   248            // worker blocks (grid = 8 fps + 248 workers = 256 CUs)
#define FP   (NP / MT)      // 16 fps points per thread
#define FW   (MT / 64)      // 8 waves
#define KJ   (NP / MT)      // 16 knn points per thread
#define KBINS 64
#define MAXC 512

// ---------------- K0: fold BN into weights, transpose to [k][o] ----------------
__global__ void fold_weights_kernel(const float* __restrict__ W, const float* __restrict__ bias,
                                    const float* __restrict__ gamma, const float* __restrict__ beta,
                                    const float* __restrict__ rmean, const float* __restrict__ rvar,
                                    float* __restrict__ Wt, float* __restrict__ Cb)
{
    int i = blockIdx.x * 256 + threadIdx.x;
    if (i < DIN * DOUT) {
        int o = i & (DOUT - 1);
        int k = i >> 7;
        float sc = gamma[o] * rsqrtf(rvar[o] + BN_EPS);
        Wt[i] = W[o * DIN + k] * sc;            // Wt[k*128 + o]
        if (i < DOUT) {
            Cb[i] = (bias[i] - rmean[i]) * sc + beta[i];
        }
    }
}

// ---------------- f64-packed argmax helpers --------------------------------------
// packed u64 = (fp32 dist bits << 32) | ~idx, as double (sign bit 0 -> numeric
// order == u64 order): fmax == (max dist, tie -> min idx).
__device__ __forceinline__ double pack_di(float d, unsigned lo)
{
    unsigned long long u = ((unsigned long long)__float_as_uint(d) << 32) | lo;
    return __longlong_as_double((long long)u);
}

template<int CTRL, int RMASK>
__device__ __forceinline__ double dpp_max_f64(double v)
{
    unsigned long long u = (unsigned long long)__double_as_longlong(v);
    unsigned hi = (unsigned)(u >> 32), lo = (unsigned)u;
    unsigned th = (unsigned)__builtin_amdgcn_update_dpp((int)hi, (int)hi, CTRL, RMASK, 0xF, false);
    unsigned tl = (unsigned)__builtin_amdgcn_update_dpp((int)lo, (int)lo, CTRL, RMASK, 0xF, false);
    double o = __longlong_as_double((long long)(((unsigned long long)th << 32) | tl));
    return fmax(v, o);
}

__device__ __forceinline__ int knn_bin(float d)
{
    int e = (int)(__float_as_uint(d) >> 23) - 90;   // monotone, clamped octave bins
    return e < 0 ? 0 : (e > 63 ? 63 : e);
}

// ---------------- mega kernel: 8 fps producers + 248 persistent workers --------
struct FpsS {
    float4 sxyz[NP];                    // 128 KB
    int sel[NS];                        // 8 KB
    unsigned long long rv64[2][FW];
};
struct KnnS {
    float sdist[NP];                    // 32 KB
    unsigned hist[32][KBINS];           // 8 KB
    float cd[MAXC];
    int   ci[MAXC];
    int   sidx[NK];
    float sf[NK][DIN];                  // 4 KB gathered feat rows
    float red[4][DOUT];                 // 2 KB cross-group max
    unsigned ccnt;
    int cut;
};
union MegaS { FpsS f; KnnS k; };
// union = ~139 KB -> 1 block/CU; grid 256 -> all blocks co-resident,
// so producer progress never depends on dispatch order (deadlock-safe).

__global__ __launch_bounds__(MT, 1)
void mega_kernel(const float* __restrict__ coords, float* __restrict__ out_coords,
                 const float* __restrict__ feat, const float* __restrict__ Wt,
                 const float* __restrict__ Cb, float* __restrict__ outF,
                 unsigned* __restrict__ flags)
{
#pragma clang fp contract(off)
    __shared__ MegaS smem;
    const int t = threadIdx.x;

    if (blockIdx.x < NB) {
        // ================= FPS producer (1 block per batch) =================
        const int b = blockIdx.x;
        const float* cb = coords + (size_t)b * NP * 3;

        for (int i = t; i < NP; i += MT)
            smem.f.sxyz[i] = make_float4(cb[i * 3 + 0], cb[i * 3 + 1], cb[i * 3 + 2], 0.0f);
        __syncthreads();

        float px[FP], py[FP], pz[FP], dist[FP];
#pragma unroll
        for (int k = 0; k < FP; ++k) {
            float4 p = smem.f.sxyz[t + k * MT];
            px[k] = p.x; py[k] = p.y; pz[k] = p.z;
            dist[k] = 1e10f;
        }

        const int wave = t >> 6, lane = t & 63;
        const unsigned nt = ~(unsigned)t;          // ~(t + k*MT) == nt - k*MT
        int cur = 0;

        for (int s = 0; s < NS; ++s) {
            if (t == 0) smem.f.sel[s] = cur;
            const float4 cc = smem.f.sxyz[cur];
            const float cx = cc.x, cy = cc.y, cz = cc.z;

            // min-dist update + f32 dual-chain max (full-rate, no per-point pack)
            float m0 = -1.0f, m1 = -1.0f;
#pragma unroll
            for (int k = 0; k < FP; ++k) {
                float dx = px[k] - cx, dy = py[k] - cy, dz = pz[k] - cz;
                float d = fmaf(dz, dz, fmaf(dy, dy, dx * dx));
                float nd = fminf(dist[k], d);
                dist[k] = nd;
                if (k & 1) m1 = fmaxf(m1, nd);
                else       m0 = fmaxf(m0, nd);
            }
            float m = fmaxf(m0, m1);
            // recover smallest k attaining m (descending cndmask chain)
            int kk = 0;
#pragma unroll
            for (int k = FP - 1; k >= 0; --k)
                if (dist[k] == m) kk = k;
            double best = pack_di(m, nt - (unsigned)(kk * MT));

            // wave argmax: 6 DPP f64-max levels -> lane 63 holds wave max
            best = dpp_max_f64<0xB1,  0xF>(best);  // quad_perm xor1
            best = dpp_max_f64<0x4E,  0xF>(best);  // quad_perm xor2
            best = dpp_max_f64<0x124, 0xF>(best);  // row_ror:4
            best = dpp_max_f64<0x128, 0xF>(best);  // row_ror:8
            best = dpp_max_f64<0x142, 0xA>(best);  // row_bcast15
            best = dpp_max_f64<0x143, 0xC>(best);  // row_bcast31

            int pb = s & 1;
            if (lane == 63) smem.f.rv64[pb][wave] = (unsigned long long)__double_as_longlong(best);
            __syncthreads();

            // cross-wave: b64 read of partial[lane&7], 4 DPP levels over row-of-16
            double g = __longlong_as_double((long long)smem.f.rv64[pb][lane & 7]);
            g = dpp_max_f64<0xB1,  0xF>(g);
            g = dpp_max_f64<0x4E,  0xF>(g);
            g = dpp_max_f64<0x124, 0xF>(g);
            g = dpp_max_f64<0x128, 0xF>(g);
            cur = (int)~(unsigned)(unsigned long long)__double_as_longlong(g);

            // publish a 32-query granule (wave 0 only: program-order release
            // covers the wave's own coord stores)
            if ((s & 31) == 31) {
                int base = s - 31;
                if (t < 32) {
                    float4 p = smem.f.sxyz[smem.f.sel[base + t]];
                    float* dst = out_coords + ((size_t)b * NS + base + t) * 3;
                    dst[0] = p.x; dst[1] = p.y; dst[2] = p.z;
                }
                if (t == 0)
                    __hip_atomic_store(&flags[b * 16], (unsigned)((s + 1) >> 5),
                                       __ATOMIC_RELEASE, __HIP_MEMORY_SCOPE_AGENT);
            }
        }
    } else {
        // ===== persistent worker: knn + fused gather/MLP/max per query =====
        const int wid = blockIdx.x - NB;           // 0..247
        const int c = t & 31;
        const int o = t & (DOUT - 1);
        const int grp = t >> 7;                    // 0..3

        for (int j = wid; j < NB * NS; j += NW) {
            const int s = j >> 3, b = j & 7;       // ascending s per worker
            const int q = b * NS + s;

            if (t == 0) {
                const unsigned need = (unsigned)(s >> 5) + 1;
                while (__hip_atomic_load(&flags[b * 16], __ATOMIC_ACQUIRE,
                                         __HIP_MEMORY_SCOPE_AGENT) < need)
                    __builtin_amdgcn_s_sleep(32);
            }
            __syncthreads();

            const float* cb = coords + (size_t)b * NP * 3;
            const float* qp = out_coords + (size_t)q * 3;
            const float qx = qp[0], qy = qp[1], qz = qp[2];

            for (int i = t; i < 32 * KBINS; i += MT) ((unsigned*)smem.k.hist)[i] = 0;
            if (t == 0) smem.k.ccnt = 0;
            __syncthreads();

            for (int jj = 0; jj < KJ; ++jj) {
                int i = t + jj * MT;
                float dx = cb[i * 3 + 0] - qx, dy = cb[i * 3 + 1] - qy, dz = cb[i * 3 + 2] - qz;
                float d = fmaf(dz, dz, fmaf(dy, dy, dx * dx));
                smem.k.sdist[i] = d;
                atomicAdd(&smem.k.hist[c][knn_bin(d)], 1u);
            }
            __syncthreads();

            if (t < 64) {
                unsigned total = 0;
#pragma unroll
                for (int cc = 0; cc < 32; ++cc) total += smem.k.hist[cc][t];
                unsigned incl = total;
#pragma unroll
                for (int off = 1; off < 64; off <<= 1) {
                    unsigned n = __shfl_up(incl, off);
                    if (t >= off) incl += n;
                }
                unsigned excl = incl - total;
                if (excl < NK && incl >= NK) smem.k.cut = t;
            }
            __syncthreads();

            const int cut = smem.k.cut;
            for (int jj = 0; jj < KJ; ++jj) {
                int i = t + jj * MT;
                float d = smem.k.sdist[i];
                if (knn_bin(d) <= cut) {
                    unsigned p = atomicAdd(&smem.k.ccnt, 1u);
                    if (p < MAXC) { smem.k.cd[p] = d; smem.k.ci[p] = i; }
                }
            }
            __syncthreads();

            // parallel rank-select: rank = #{(dj,ij) < (d,i)}; unique ranks -> LDS
            int cnt = (int)(smem.k.ccnt < (unsigned)MAXC ? smem.k.ccnt : (unsigned)MAXC);
            for (int p = t; p < cnt; p += MT) {
                float d = smem.k.cd[p]; int idx = smem.k.ci[p];
                int rank = 0;
                for (int jj = 0; jj < cnt; ++jj) {
                    float dj = smem.k.cd[jj]; int ij = smem.k.ci[jj];
                    rank += (dj < d || (dj == d && ij < idx)) ? 1 : 0;
                }
                if (rank < NK) smem.k.sidx[rank] = idx;
            }
            __syncthreads();

            // gather 16 neighbor feat rows (coalesced 256-B rows)
#pragma unroll
            for (int rr = 0; rr < 2; ++rr) {
                int row = (t >> 6) + rr * 8;       // 0..15
                smem.k.sf[row][t & 63] =
                    feat[((size_t)b * NP + smem.k.sidx[row]) * DIN + (t & 63)];
            }
            __syncthreads();

            // fused MLP+relu+max: each thread handles out-channel o, neighbors
            // {grp, grp+4, grp+8, grp+12}; cross-group max via LDS
            const float cb0 = Cb[o];
            float mx = -3.4e38f;
#pragma unroll
            for (int nn = 0; nn < 4; ++nn) {
                const float4* f4 = (const float4*)smem.k.sf[grp + nn * 4];
                float acc = cb0;
#pragma unroll
                for (int k4 = 0; k4 < DIN / 4; ++k4) {
                    float4 f = f4[k4];
                    acc = fmaf(f.x, Wt[(k4 * 4 + 0) * DOUT + o], acc);
                    acc = fmaf(f.y, Wt[(k4 * 4 + 1) * DOUT + o], acc);
                    acc = fmaf(f.z, Wt[(k4 * 4 + 2) * DOUT + o], acc);
                    acc = fmaf(f.w, Wt[(k4 * 4 + 3) * DOUT + o], acc);
                }
                mx = fmaxf(mx, fmaxf(acc, 0.0f));
            }
            smem.k.red[grp][o] = mx;
            __syncthreads();

            if (t < DOUT) {
                float v = fmaxf(fmaxf(smem.k.red[0][t], smem.k.red[1][t]),
                                fmaxf(smem.k.red[2][t], smem.k.red[3][t]));
                outF[(size_t)q * DOUT + t] = v;
            }
            __syncthreads();
        }
    }
}

extern "C" void kernel_launch(void* const* d_in, const int* in_sizes, int n_in,
                              void* d_out, int out_size, void* d_ws, size_t ws_size,
                              hipStream_t stream)
{
    const float* coords = (const float*)d_in[0];
    const float* feat   = (const float*)d_in[1];
    const float* W      = (const float*)d_in[2];
    const float* bias   = (const float*)d_in[3];
    const float* gamma  = (const float*)d_in[4];
    const float* beta   = (const float*)d_in[5];
    const float* rmean  = (const float*)d_in[6];
    const float* rvar   = (const float*)d_in[7];

    float* out_coords = (float*)d_out;                    // [8,2048,3]
    float* out_feat   = out_coords + (size_t)NB * NS * 3; // [8,2048,128]

    char* ws = (char*)d_ws;
    float*    Wt    = (float*)ws;                         // 32 KB
    float*    Cb    = (float*)(ws + 32768);               // 512 B
    unsigned* flags = (unsigned*)(ws + 40960);            // 8 flags, 64B apart

    hipMemsetAsync(flags, 0, 8 * 16 * sizeof(unsigned), stream);
    fold_weights_kernel<<<(DIN * DOUT + 255) / 256, 256, 0, stream>>>(
        W, bias, gamma, beta, rmean, rvar, Wt, Cb);
    mega_kernel<<<NB + NW, MT, 0, stream>>>(
        coords, out_coords, feat, Wt, Cb, out_feat, flags);
}